// Round 1
// baseline (558.865 us; speedup 1.0000x reference)
//
#include <hip/hip_runtime.h>
#include <hip/hip_bf16.h>

typedef short v8s __attribute__((ext_vector_type(8)));
typedef float v4f __attribute__((ext_vector_type(4)));

#define MFMA_B16(A, B, C) __builtin_amdgcn_mfma_f32_16x16x32_bf16((A), (B), (C), 0, 0, 0)

#define NB   8192
#define XW   8704
#define GF   256
#define GH   52
#define GO   5
#define UFK  512
#define UHN  103
#define UON  20

__device__ __forceinline__ unsigned short f2bf(float f) {
  union { __hip_bfloat16 h; unsigned short u; } cv;
  cv.h = __float2bfloat16(f);
  return cv.u;
}

__device__ __forceinline__ float elu1(float y) {
  return y > 0.f ? y : (__expf(y) - 1.f);
}

__device__ __forceinline__ v8s pack8(const float* p) {
  float4 q0 = *(const float4*)p;
  float4 q1 = *(const float4*)(p + 4);
  v8s a;
  a[0] = (short)f2bf(q0.x); a[1] = (short)f2bf(q0.y);
  a[2] = (short)f2bf(q0.z); a[3] = (short)f2bf(q0.w);
  a[4] = (short)f2bf(q1.x); a[5] = (short)f2bf(q1.y);
  a[6] = (short)f2bf(q1.z); a[7] = (short)f2bf(q1.w);
  return a;
}

// ---------------- group-head kernel: 32 MLPs of 256->52->52->5 -------------
// grid: (NB/64, 32), block: 256 threads (4 waves, 16 rows per wave)
__global__ __launch_bounds__(256) void group_kernel(
    const float* __restrict__ x,  const float* __restrict__ W1,
    const float* __restrict__ b1, const float* __restrict__ W2,
    const float* __restrict__ b2, const float* __restrict__ W3,
    const float* __restrict__ b3, const float* __restrict__ outW,
    float* __restrict__ out)
{
  const int g    = blockIdx.y;
  const int row0 = blockIdx.x * 64;
  const int tid  = threadIdx.x;
  const int wave = tid >> 6;
  const int lane = tid & 63;
  const int l15  = lane & 15;
  const int l4   = lane >> 4;

  // col-major ("transposed") weight tiles, padded strides -> 2-way bank max
  __shared__ __align__(16) unsigned short w1t[64 * 264];      // [h][f], stride 264 shorts
  __shared__ __align__(16) unsigned short w2t[64 * 72];       // [k][h], stride 72
  __shared__ __align__(16) unsigned short w3t[16 * 72];       // [o][h], stride 72
  __shared__ __align__(16) unsigned short hbuf[4][16 * 72];   // per-wave [row][col]
  __shared__ float bias1[64], bias2[64], bias3[16];

  // zero ALL weight LDS first (padded cols/rows must be 0.0, never garbage/NaN)
  {
    unsigned int* p1 = (unsigned int*)w1t;
    for (int i = tid; i < 64 * 264 / 2; i += 256) p1[i] = 0u;
    unsigned int* p2 = (unsigned int*)w2t;
    for (int i = tid; i < 64 * 72 / 2; i += 256) p2[i] = 0u;
    unsigned int* p3 = (unsigned int*)w3t;
    for (int i = tid; i < 16 * 72 / 2; i += 256) p3[i] = 0u;
  }
  __syncthreads();

  // stage weights fp32 -> bf16, transposed (coalesced global reads)
  for (int i = tid; i < GF * GH; i += 256) {
    int f = i / GH, h = i % GH;
    w1t[h * 264 + f] = f2bf(W1[g * (GF * GH) + i]);
  }
  for (int i = tid; i < GH * GH; i += 256) {
    int h = i / GH, k = i % GH;
    w2t[k * 72 + h] = f2bf(W2[g * (GH * GH) + i]);
  }
  for (int i = tid; i < GH * GO; i += 256) {
    int h = i / GO, o = i % GO;
    w3t[o * 72 + h] = f2bf(W3[g * (GH * GO) + i]);
  }
  if (tid < 64)        { bias1[tid] = (tid < GH) ? b1[g * GH + tid] : 0.f; }
  else if (tid < 128)  { int c = tid - 64;  bias2[c] = (c < GH) ? b2[g * GH + c] : 0.f; }
  else if (tid < 144)  { int c = tid - 128; bias3[c] = (c < GO) ? b3[g * GO + c] : 0.f; }
  __syncthreads();

  const int  row  = row0 + wave * 16 + l15;
  const float* xrow = x + (long)row * XW + g * GF;

  const v4f z = {0.f, 0.f, 0.f, 0.f};

  // ---- layer 1: X(16x256) @ W1(256x64) ----
  v4f acc1[4] = {z, z, z, z};
#pragma unroll
  for (int kk = 0; kk < 8; ++kk) {
    v8s a = pack8(xrow + kk * 32 + l4 * 8);
#pragma unroll
    for (int n = 0; n < 4; ++n) {
      v8s b = *(const v8s*)&w1t[(n * 16 + l15) * 264 + kk * 32 + l4 * 8];
      acc1[n] = MFMA_B16(a, b, acc1[n]);
    }
  }
#pragma unroll
  for (int n = 0; n < 4; ++n) {
    int col = n * 16 + l15;
    float bb = bias1[col];
#pragma unroll
    for (int r = 0; r < 4; ++r) {
      float h = elu1(acc1[n][r] + bb);
      hbuf[wave][(l4 * 4 + r) * 72 + col] = f2bf(h);
    }
  }
  __syncthreads();

  // ---- layer 2: H1(16x64) @ W2(64x64) ----
  v4f acc2[4] = {z, z, z, z};
#pragma unroll
  for (int kk = 0; kk < 2; ++kk) {
    v8s a = *(const v8s*)&hbuf[wave][l15 * 72 + kk * 32 + l4 * 8];
#pragma unroll
    for (int n = 0; n < 4; ++n) {
      v8s b = *(const v8s*)&w2t[(n * 16 + l15) * 72 + kk * 32 + l4 * 8];
      acc2[n] = MFMA_B16(a, b, acc2[n]);
    }
  }
  __syncthreads();
#pragma unroll
  for (int n = 0; n < 4; ++n) {
    int col = n * 16 + l15;
    float bb = bias2[col];
#pragma unroll
    for (int r = 0; r < 4; ++r) {
      float h = elu1(acc2[n][r] + bb);
      hbuf[wave][(l4 * 4 + r) * 72 + col] = f2bf(h);
    }
  }
  __syncthreads();

  // ---- layer 3: H2(16x64) @ W3(64x16) ----
  v4f acc3 = z;
#pragma unroll
  for (int kk = 0; kk < 2; ++kk) {
    v8s a = *(const v8s*)&hbuf[wave][l15 * 72 + kk * 32 + l4 * 8];
    v8s b = *(const v8s*)&w3t[l15 * 72 + kk * 32 + l4 * 8];
    acc3 = MFMA_B16(a, b, acc3);
  }

  // epilogue: h3 * outW[g*5+o], reduce over the 16 "col" lanes, atomicAdd
  float ow = (l15 < GO) ? outW[g * GO + l15] : 0.f;
  float bb = bias3[l15];
  float v0 = elu1(acc3[0] + bb) * ow;
  float v1 = elu1(acc3[1] + bb) * ow;
  float v2 = elu1(acc3[2] + bb) * ow;
  float v3 = elu1(acc3[3] + bb) * ow;
#pragma unroll
  for (int off = 1; off < 16; off <<= 1) {
    v0 += __shfl_xor(v0, off, 64);
    v1 += __shfl_xor(v1, off, 64);
    v2 += __shfl_xor(v2, off, 64);
    v3 += __shfl_xor(v3, off, 64);
  }
  if (l15 < 4) {
    float val = (l15 == 0) ? v0 : (l15 == 1) ? v1 : (l15 == 2) ? v2 : v3;
    atomicAdd(&out[row0 + wave * 16 + l4 * 4 + l15], val);
  }
}

// ---------------- universal MLP kernel: 512->103->103->20 ------------------
// grid: (NB/32), block: 128 threads (2 waves, 16 rows per wave)
__global__ __launch_bounds__(128) void universal_kernel(
    const float* __restrict__ x,   const float* __restrict__ uW1,
    const float* __restrict__ ub1, const float* __restrict__ uW2,
    const float* __restrict__ ub2, const float* __restrict__ uW3,
    const float* __restrict__ ub3, const float* __restrict__ outW,
    float* __restrict__ out)
{
  const int row0 = blockIdx.x * 32;
  const int tid  = threadIdx.x;
  const int wave = tid >> 6;
  const int lane = tid & 63;
  const int l15  = lane & 15;
  const int l4   = lane >> 4;

  __shared__ __align__(16) unsigned short wub[128 * 136];      // [col][k], stride 136 shorts
  __shared__ __align__(16) unsigned short hbufu[2][16 * 136];  // per-wave [row][col]
  __shared__ float biasu[128];

  {
    unsigned int* p = (unsigned int*)wub;
    for (int i = tid; i < 128 * 136 / 2; i += 128) p[i] = 0u;
  }
  biasu[tid] = (tid < UHN) ? ub1[tid] : 0.f;
  __syncthreads();

  const int  row  = row0 + wave * 16 + l15;
  const float* xrow = x + (long)row * XW + 8192;

  const v4f z = {0.f, 0.f, 0.f, 0.f};

  // ---- layer 1: X(16x512) @ uW1(512x128), K staged in 4 chunks of 128 ----
  v4f acc1[8] = {z, z, z, z, z, z, z, z};
  for (int c = 0; c < 4; ++c) {
    for (int i = tid; i < 128 * UHN; i += 128) {
      int kl = i / UHN, h = i % UHN;
      wub[h * 136 + kl] = f2bf(uW1[(c * 128 + kl) * UHN + h]);
    }
    __syncthreads();
#pragma unroll
    for (int kk = 0; kk < 4; ++kk) {
      v8s a = pack8(xrow + c * 128 + kk * 32 + l4 * 8);
#pragma unroll
      for (int n = 0; n < 8; ++n) {
        v8s b = *(const v8s*)&wub[(n * 16 + l15) * 136 + kk * 32 + l4 * 8];
        acc1[n] = MFMA_B16(a, b, acc1[n]);
      }
    }
    __syncthreads();
  }
#pragma unroll
  for (int n = 0; n < 8; ++n) {
    int col = n * 16 + l15;
    float bb = biasu[col];
#pragma unroll
    for (int r = 0; r < 4; ++r) {
      float h = elu1(acc1[n][r] + bb);
      hbufu[wave][(l4 * 4 + r) * 136 + col] = f2bf(h);
    }
  }
  __syncthreads();

  // ---- restage uW2 (103x103) ----
  for (int i = tid; i < UHN * UHN; i += 128) {
    int h = i / UHN, k = i % UHN;
    wub[k * 136 + h] = f2bf(uW2[i]);
  }
  biasu[tid] = (tid < UHN) ? ub2[tid] : 0.f;
  __syncthreads();

  // ---- layer 2: H1(16x128) @ uW2(128x128) ----
  v4f acc2[8] = {z, z, z, z, z, z, z, z};
#pragma unroll
  for (int kk = 0; kk < 4; ++kk) {
    v8s a = *(const v8s*)&hbufu[wave][l15 * 136 + kk * 32 + l4 * 8];
#pragma unroll
    for (int n = 0; n < 8; ++n) {
      v8s b = *(const v8s*)&wub[(n * 16 + l15) * 136 + kk * 32 + l4 * 8];
      acc2[n] = MFMA_B16(a, b, acc2[n]);
    }
  }
  __syncthreads();
#pragma unroll
  for (int n = 0; n < 8; ++n) {
    int col = n * 16 + l15;
    float bb = biasu[col];
#pragma unroll
    for (int r = 0; r < 4; ++r) {
      float h = elu1(acc2[n][r] + bb);
      hbufu[wave][(l4 * 4 + r) * 136 + col] = f2bf(h);
    }
  }
  __syncthreads();

  // ---- restage uW3 (103x20); zero cols 20..31 (stale uW2 there) ----
  {
    unsigned int* p = (unsigned int*)(wub + 20 * 136);
    for (int i = tid; i < 12 * 136 / 2; i += 128) p[i] = 0u;
  }
  for (int i = tid; i < UHN * UON; i += 128) {
    int h = i / UON, o = i % UON;
    wub[o * 136 + h] = f2bf(uW3[i]);
  }
  if (tid < 32) biasu[tid] = (tid < UON) ? ub3[tid] : 0.f;
  __syncthreads();

  // ---- layer 3: H2(16x128) @ uW3(128x32) ----
  v4f acc3[2] = {z, z};
#pragma unroll
  for (int kk = 0; kk < 4; ++kk) {
    v8s a = *(const v8s*)&hbufu[wave][l15 * 136 + kk * 32 + l4 * 8];
#pragma unroll
    for (int n = 0; n < 2; ++n) {
      v8s b = *(const v8s*)&wub[(n * 16 + l15) * 136 + kk * 32 + l4 * 8];
      acc3[n] = MFMA_B16(a, b, acc3[n]);
    }
  }

  float ow0 = (l15 < UON)      ? outW[160 + l15]      : 0.f;
  float ow1 = (16 + l15 < UON) ? outW[160 + 16 + l15] : 0.f;
  float bb0 = biasu[l15];
  float bb1 = biasu[16 + l15];
  float v0 = elu1(acc3[0][0] + bb0) * ow0 + elu1(acc3[1][0] + bb1) * ow1;
  float v1 = elu1(acc3[0][1] + bb0) * ow0 + elu1(acc3[1][1] + bb1) * ow1;
  float v2 = elu1(acc3[0][2] + bb0) * ow0 + elu1(acc3[1][2] + bb1) * ow1;
  float v3 = elu1(acc3[0][3] + bb0) * ow0 + elu1(acc3[1][3] + bb1) * ow1;
#pragma unroll
  for (int off = 1; off < 16; off <<= 1) {
    v0 += __shfl_xor(v0, off, 64);
    v1 += __shfl_xor(v1, off, 64);
    v2 += __shfl_xor(v2, off, 64);
    v3 += __shfl_xor(v3, off, 64);
  }
  if (l15 < 4) {
    float val = (l15 == 0) ? v0 : (l15 == 1) ? v1 : (l15 == 2) ? v2 : v3;
    atomicAdd(&out[row0 + wave * 16 + l4 * 4 + l15], val);
  }
}

extern "C" void kernel_launch(void* const* d_in, const int* in_sizes, int n_in,
                              void* d_out, int out_size, void* d_ws, size_t ws_size,
                              hipStream_t stream) {
  const float* x    = (const float*)d_in[0];
  const float* W1   = (const float*)d_in[1];
  const float* b1   = (const float*)d_in[2];
  const float* W2   = (const float*)d_in[3];
  const float* b2   = (const float*)d_in[4];
  const float* W3   = (const float*)d_in[5];
  const float* b3   = (const float*)d_in[6];
  const float* uW1  = (const float*)d_in[7];
  const float* ub1  = (const float*)d_in[8];
  const float* uW2  = (const float*)d_in[9];
  const float* ub2  = (const float*)d_in[10];
  const float* uW3  = (const float*)d_in[11];
  const float* ub3  = (const float*)d_in[12];
  const float* outW = (const float*)d_in[13];
  float* out = (float*)d_out;

  hipMemsetAsync(out, 0, (size_t)out_size * sizeof(float), stream);

  dim3 ggrid(NB / 64, 32);
  group_kernel<<<ggrid, 256, 0, stream>>>(x, W1, b1, W2, b2, W3, b3, outW, out);
  universal_kernel<<<NB / 32, 128, 0, stream>>>(x, uW1, ub1, uW2, ub2, uW3, ub3, outW, out);
}

// Round 3
// 452.446 us; speedup vs baseline: 1.2352x; 1.2352x over previous
//
#include <hip/hip_runtime.h>
#include <hip/hip_bf16.h>

typedef short v8s __attribute__((ext_vector_type(8)));
typedef float v4f __attribute__((ext_vector_type(4)));

#define MFMA_B16(A, B, C) __builtin_amdgcn_mfma_f32_16x16x32_bf16((A), (B), (C), 0, 0, 0)

#define NB   8192
#define XW   8704

// ws layout (in shorts). Per-group blob = W1t[64][264] + W2t[64][72] + W3t[16][72]
#define GW1     16896           // 64*264
#define GW12    21504           // + 64*72
#define GW_STRIDE 22656         // + 16*72
#define OFF_U1  724992          // 32*22656
#define OFF_U2  791552          // + 128*520
#define OFF_U3  808960          // + 128*136
#define WS_TOTAL 813312         // + 32*136

__device__ __forceinline__ unsigned short f2bf(float f) {
  union { __hip_bfloat16 h; unsigned short u; } cv;
  cv.h = __float2bfloat16(f);
  return cv.u;
}

__device__ __forceinline__ float elu1(float y) {
  return y > 0.f ? y : (__expf(y) - 1.f);
}

__device__ __forceinline__ v8s pack8(const float* p) {
  float4 q0 = *(const float4*)p;
  float4 q1 = *(const float4*)(p + 4);
  v8s a;
  a[0] = (short)f2bf(q0.x); a[1] = (short)f2bf(q0.y);
  a[2] = (short)f2bf(q0.z); a[3] = (short)f2bf(q0.w);
  a[4] = (short)f2bf(q1.x); a[5] = (short)f2bf(q1.y);
  a[6] = (short)f2bf(q1.z); a[7] = (short)f2bf(q1.w);
  return a;
}

// -------- prep: convert all weights fp32 -> bf16 into ws, transposed+padded --------
__global__ __launch_bounds__(256) void prep_kernel(
    const float* __restrict__ W1, const float* __restrict__ W2,
    const float* __restrict__ W3, const float* __restrict__ uW1,
    const float* __restrict__ uW2, const float* __restrict__ uW3,
    unsigned short* __restrict__ ws16)
{
  int i = blockIdx.x * 256 + threadIdx.x;
  if (i >= WS_TOTAL) return;
  float val = 0.f;
  if (i < OFF_U1) {
    int g = i / GW_STRIDE, r = i % GW_STRIDE;
    if (r < GW1)        { int h = r / 264, f = r % 264;            if (h < 52 && f < 256) val = W1[(g * 256 + f) * 52 + h]; }
    else if (r < GW12)  { int r2 = r - GW1;  int k = r2 / 72, h = r2 % 72; if (k < 52 && h < 52) val = W2[g * 2704 + h * 52 + k]; }
    else                { int r3 = r - GW12; int o = r3 / 72, h = r3 % 72; if (o < 5  && h < 52) val = W3[g * 260 + h * 5 + o]; }
  } else if (i < OFF_U2) {
    int j = i - OFF_U1; int h = j / 520, k = j % 520; if (h < 103 && k < 512) val = uW1[k * 103 + h];
  } else if (i < OFF_U3) {
    int j = i - OFF_U2; int k2 = j / 136, h = j % 136; if (k2 < 103 && h < 103) val = uW2[h * 103 + k2];
  } else {
    int j = i - OFF_U3; int o = j / 136, h = j % 136; if (o < 20 && h < 103) val = uW3[h * 20 + o];
  }
  ws16[i] = f2bf(val);
}

// -------- fused main kernel: 64 universal blocks + 512 group blocks --------
// group block: (g, s) stages weights ONCE, loops 8 row-tiles of 64 rows.
// universal block: weights read direct from L2-resident ws, no staging.
__global__ __launch_bounds__(256) void fused_kernel(
    const float* __restrict__ x,
    const unsigned short* __restrict__ ws16,
    const float* __restrict__ b1, const float* __restrict__ b2,
    const float* __restrict__ b3,
    const float* __restrict__ ub1, const float* __restrict__ ub2,
    const float* __restrict__ ub3,
    const float* __restrict__ outW,
    float* __restrict__ out)
{
  __shared__ __align__(16) unsigned char smem[55104];

  const int bid  = blockIdx.x;
  const int tid  = threadIdx.x;
  const int wave = tid >> 6;
  const int lane = tid & 63;
  const int l15  = lane & 15;
  const int l4   = lane >> 4;
  const v4f z = {0.f, 0.f, 0.f, 0.f};

  if (bid < 64) {
    // ---------------- universal role: 512->103->103->20 ----------------
    const unsigned short* u1 = ws16 + OFF_U1;
    const unsigned short* u2 = ws16 + OFF_U2;
    const unsigned short* u3 = ws16 + OFF_U3;
    unsigned short* hbufu = (unsigned short*)smem + wave * 2176;   // [16][136]

    for (int tt = 0; tt < 2; ++tt) {
      const int rowbase = bid * 128 + wave * 32 + tt * 16;
      const float* xrow = x + (size_t)(rowbase + l15) * XW + 8192;

      // ---- layer 1: X(16x512) @ uW1(512x128), B-frags direct from L2 ----
      v4f acc1[8] = {z, z, z, z, z, z, z, z};
#pragma unroll 4
      for (int kk = 0; kk < 16; ++kk) {
        v8s a = pack8(xrow + kk * 32 + l4 * 8);
#pragma unroll
        for (int n = 0; n < 8; ++n) {
          v8s b = *(const v8s*)&u1[(n * 16 + l15) * 520 + kk * 32 + l4 * 8];
          acc1[n] = MFMA_B16(a, b, acc1[n]);
        }
      }
#pragma unroll
      for (int n = 0; n < 8; ++n) {
        int col = n * 16 + l15;
        float bb = (col < 103) ? ub1[col] : 0.f;
#pragma unroll
        for (int r = 0; r < 4; ++r)
          hbufu[(l4 * 4 + r) * 136 + col] = f2bf(elu1(acc1[n][r] + bb));
      }

      // ---- layer 2: H1(16x128) @ uW2(128x128) ----
      v4f acc2[8] = {z, z, z, z, z, z, z, z};
#pragma unroll
      for (int kk = 0; kk < 4; ++kk) {
        v8s a = *(const v8s*)&hbufu[l15 * 136 + kk * 32 + l4 * 8];
#pragma unroll
        for (int n = 0; n < 8; ++n) {
          v8s b = *(const v8s*)&u2[(n * 16 + l15) * 136 + kk * 32 + l4 * 8];
          acc2[n] = MFMA_B16(a, b, acc2[n]);
        }
      }
#pragma unroll
      for (int n = 0; n < 8; ++n) {
        int col = n * 16 + l15;
        float bb = (col < 103) ? ub2[col] : 0.f;
#pragma unroll
        for (int r = 0; r < 4; ++r)
          hbufu[(l4 * 4 + r) * 136 + col] = f2bf(elu1(acc2[n][r] + bb));
      }

      // ---- layer 3: H2(16x128) @ uW3(128x32) ----
      v4f acc3[2] = {z, z};
#pragma unroll
      for (int kk = 0; kk < 4; ++kk) {
        v8s a = *(const v8s*)&hbufu[l15 * 136 + kk * 32 + l4 * 8];
#pragma unroll
        for (int n = 0; n < 2; ++n) {
          v8s b = *(const v8s*)&u3[(n * 16 + l15) * 136 + kk * 32 + l4 * 8];
          acc3[n] = MFMA_B16(a, b, acc3[n]);
        }
      }

      float ow0 = (l15 < 20)      ? outW[160 + l15]      : 0.f;
      float ow1 = (16 + l15 < 20) ? outW[160 + 16 + l15] : 0.f;
      float bb0 = (l15 < 20)      ? ub3[l15]             : 0.f;
      float bb1 = (16 + l15 < 20) ? ub3[16 + l15]        : 0.f;
      float v0 = elu1(acc3[0][0] + bb0) * ow0 + elu1(acc3[1][0] + bb1) * ow1;
      float v1 = elu1(acc3[0][1] + bb0) * ow0 + elu1(acc3[1][1] + bb1) * ow1;
      float v2 = elu1(acc3[0][2] + bb0) * ow0 + elu1(acc3[1][2] + bb1) * ow1;
      float v3 = elu1(acc3[0][3] + bb0) * ow0 + elu1(acc3[1][3] + bb1) * ow1;
#pragma unroll
      for (int off = 1; off < 16; off <<= 1) {
        v0 += __shfl_xor(v0, off, 64);
        v1 += __shfl_xor(v1, off, 64);
        v2 += __shfl_xor(v2, off, 64);
        v3 += __shfl_xor(v3, off, 64);
      }
      if (l15 < 4) {
        float val = (l15 == 0) ? v0 : (l15 == 1) ? v1 : (l15 == 2) ? v2 : v3;
        atomicAdd(&out[rowbase + l4 * 4 + l15], val);
      }
    }
    return;
  }

  // ---------------- group role: 32 MLPs of 256->52->52->5 ----------------
  const int gbid = bid - 64;
  const int g = gbid & 31;
  const int s = gbid >> 5;        // 0..15, tiles t = s, s+16, ...

  const unsigned short* w1t = (const unsigned short*)smem;            // [64][264]
  const unsigned short* w2t = (const unsigned short*)(smem + 33792);  // [64][72]
  const unsigned short* w3t = (const unsigned short*)(smem + 43008);  // [16][72]
  unsigned short* hbuf = (unsigned short*)(smem + 45312) + wave * 1152;  // [16][72]
  float* bias1 = (float*)(smem + 54528);
  float* bias2 = (float*)(smem + 54784);
  float* bias3 = (float*)(smem + 55040);

  // stage: one flat 45KB vector copy from the pre-converted ws blob
  {
    const v8s* wsg = (const v8s*)(ws16 + (size_t)g * GW_STRIDE);
    v8s* sv = (v8s*)smem;
    for (int i = tid; i < 2832; i += 256) sv[i] = wsg[i];
    if (tid < 64)       { bias1[tid] = (tid < 52) ? b1[g * 52 + tid] : 0.f; }
    else if (tid < 128) { int c = tid - 64;  bias2[c] = (c < 52) ? b2[g * 52 + c] : 0.f; }
    else if (tid < 144) { int c = tid - 128; bias3[c] = (c < 5)  ? b3[g * 5 + c]  : 0.f; }
  }
  __syncthreads();

  for (int t = s; t < 128; t += 16) {
    const int row0 = t * 64;
    const float* xrow = x + (size_t)(row0 + wave * 16 + l15) * XW + g * 256;

    // ---- layer 1: X(16x256) @ W1(256x64) ----
    v4f acc1[4] = {z, z, z, z};
#pragma unroll
    for (int kk = 0; kk < 8; ++kk) {
      v8s a = pack8(xrow + kk * 32 + l4 * 8);
#pragma unroll
      for (int n = 0; n < 4; ++n) {
        v8s b = *(const v8s*)&w1t[(n * 16 + l15) * 264 + kk * 32 + l4 * 8];
        acc1[n] = MFMA_B16(a, b, acc1[n]);
      }
    }
#pragma unroll
    for (int n = 0; n < 4; ++n) {
      int col = n * 16 + l15;
      float bb = bias1[col];
#pragma unroll
      for (int r = 0; r < 4; ++r)
        hbuf[(l4 * 4 + r) * 72 + col] = f2bf(elu1(acc1[n][r] + bb));
    }

    // ---- layer 2: H1(16x64) @ W2(64x64) ----
    v4f acc2[4] = {z, z, z, z};
#pragma unroll
    for (int kk = 0; kk < 2; ++kk) {
      v8s a = *(const v8s*)&hbuf[l15 * 72 + kk * 32 + l4 * 8];
#pragma unroll
      for (int n = 0; n < 4; ++n) {
        v8s b = *(const v8s*)&w2t[(n * 16 + l15) * 72 + kk * 32 + l4 * 8];
        acc2[n] = MFMA_B16(a, b, acc2[n]);
      }
    }
#pragma unroll
    for (int n = 0; n < 4; ++n) {
      int col = n * 16 + l15;
      float bb = bias2[col];
#pragma unroll
      for (int r = 0; r < 4; ++r)
        hbuf[(l4 * 4 + r) * 72 + col] = f2bf(elu1(acc2[n][r] + bb));
    }

    // ---- layer 3: H2(16x64) @ W3(64x16) ----
    v4f acc3 = z;
#pragma unroll
    for (int kk = 0; kk < 2; ++kk) {
      v8s a = *(const v8s*)&hbuf[l15 * 72 + kk * 32 + l4 * 8];
      v8s b = *(const v8s*)&w3t[l15 * 72 + kk * 32 + l4 * 8];
      acc3 = MFMA_B16(a, b, acc3);
    }

    float ow = (l15 < 5) ? outW[g * 5 + l15] : 0.f;
    float bb = bias3[l15];
    float v0 = elu1(acc3[0] + bb) * ow;
    float v1 = elu1(acc3[1] + bb) * ow;
    float v2 = elu1(acc3[2] + bb) * ow;
    float v3 = elu1(acc3[3] + bb) * ow;
#pragma unroll
    for (int off = 1; off < 16; off <<= 1) {
      v0 += __shfl_xor(v0, off, 64);
      v1 += __shfl_xor(v1, off, 64);
      v2 += __shfl_xor(v2, off, 64);
      v3 += __shfl_xor(v3, off, 64);
    }
    if (l15 < 4) {
      float val = (l15 == 0) ? v0 : (l15 == 1) ? v1 : (l15 == 2) ? v2 : v3;
      atomicAdd(&out[row0 + wave * 16 + l4 * 4 + l15], val);
    }
  }
}

extern "C" void kernel_launch(void* const* d_in, const int* in_sizes, int n_in,
                              void* d_out, int out_size, void* d_ws, size_t ws_size,
                              hipStream_t stream) {
  const float* x    = (const float*)d_in[0];
  const float* W1   = (const float*)d_in[1];
  const float* b1   = (const float*)d_in[2];
  const float* W2   = (const float*)d_in[3];
  const float* b2   = (const float*)d_in[4];
  const float* W3   = (const float*)d_in[5];
  const float* b3   = (const float*)d_in[6];
  const float* uW1  = (const float*)d_in[7];
  const float* ub1  = (const float*)d_in[8];
  const float* uW2  = (const float*)d_in[9];
  const float* ub2  = (const float*)d_in[10];
  const float* uW3  = (const float*)d_in[11];
  const float* ub3  = (const float*)d_in[12];
  const float* outW = (const float*)d_in[13];
  float* out = (float*)d_out;
  unsigned short* ws16 = (unsigned short*)d_ws;

  hipMemsetAsync(out, 0, (size_t)out_size * sizeof(float), stream);
  prep_kernel<<<(WS_TOTAL + 255) / 256, 256, 0, stream>>>(W1, W2, W3, uW1, uW2, uW3, ws16);
  fused_kernel<<<576, 256, 0, stream>>>(x, ws16, b1, b2, b3, ub1, ub2, ub3, outW, out);
}